// Round 5
// baseline (734.702 us; speedup 1.0000x reference)
//
#include <hip/hip_runtime.h>
#include <hip/hip_fp16.h>

#define NB 8          // batch
#define NS 4096       // seq len
#define NH 2048       // hidden
#define NDH 64        // selector hidden dim
#define NK 256        // top-k
#define KS 4          // split-K factor
#define KCH (NH / KS) // 512 k per block

// ---------------------------------------------------------------------------
// K1 "streaming row GEMM": partial = hs @ w1 over this block's k-chunk,
// fused with fp16-rounded copy of hs into out0. ZERO LDS, ZERO barriers.
//
// Why: rounds 1-4 showed the LDS-tiled version is LDS-read-instruction
// bound (r1 4-tok tile: 48 b128/stage ~ 123 us model vs 117 measured;
// r4 2-tok tile: 80 b128/stage ~ 205 model vs 175 measured). Under the
// spill-safe register budget the LDS-instr:FMA ratio was already optimal,
// so the fix is to not use LDS at all:
//  - each lane owns ONE token row; its 8 float4 loads per 32-k chunk are
//    both the FMA A-operand and the fp16-rounded copy-out source.
//  - W is wave-uniform: wave-pair w>>1 owns dh half [32*(w>>1), +32);
//    readfirstlane makes the offset scalar so w1[k][half] promotes to
//    s_load / broadcast VMEM (L1-hot, 128 KB slice) -> no LDS reads.
//  - twin waves (two dh halves) read the same 128 rows; 128 rows x 128 B
//    = 16 KB fits L1, so HBM fetch is unchanged.
//  - per-(token,dh) accumulation is strictly ascending k over the same
//    512-k chunk as all previous rounds -> bit-identical logits/top-k.
// Live set ~ acc 32 + 8 inflight + addr ~= 55 VGPR: spill-proof under
// every allocator cap observed (64/88/104).
// ---------------------------------------------------------------------------
__global__ __launch_bounds__(256) void k_sel_gemm(
    const float* __restrict__ hs, const float* __restrict__ w1,
    float* __restrict__ out0, float* __restrict__ part)
{
    const int tid  = threadIdx.x;
    const int lane = tid & 63;
    const int w    = tid >> 6;     // wave 0..3
    const int tsub = w & 1;        // token sub-block within tile
    const int dhH  = w >> 1;       // dh half: 0 -> dh 0..31, 1 -> dh 32..63

    const int tile = blockIdx.x & 255;   // 256 tiles x 128 tokens
    const int kc   = blockIdx.x >> 8;    // split-K chunk

    const int token = tile * 128 + tsub * 64 + lane;
    const long long rowOff = (long long)token * NH + (long long)kc * KCH;
    const float* arow = hs + rowOff;
    float*       orow = out0 + rowOff;

    const int dhOff = __builtin_amdgcn_readfirstlane(dhH * 32);
    const float* wbase = w1 + (long long)kc * KCH * NDH + dhOff;

    float acc[32];
#pragma unroll
    for (int j = 0; j < 32; ++j) acc[j] = 0.0f;

    // copy-out duty split by k-half between the twin dh-waves
    const int storeLo = (dhH == 0) ? 0 : (KCH / 2);
    const int storeHi = storeLo + KCH / 2;

    for (int k0 = 0; k0 < KCH; k0 += 8) {
        const float4 a0 = *reinterpret_cast<const float4*>(arow + k0);
        const float4 a1 = *reinterpret_cast<const float4*>(arow + k0 + 4);

        if (k0 >= storeLo && k0 < storeHi) {
            float4 o0, o1;
            o0.x = __half2float(__float2half(a0.x));
            o0.y = __half2float(__float2half(a0.y));
            o0.z = __half2float(__float2half(a0.z));
            o0.w = __half2float(__float2half(a0.w));
            o1.x = __half2float(__float2half(a1.x));
            o1.y = __half2float(__float2half(a1.y));
            o1.z = __half2float(__float2half(a1.z));
            o1.w = __half2float(__float2half(a1.w));
            *reinterpret_cast<float4*>(orow + k0)     = o0;
            *reinterpret_cast<float4*>(orow + k0 + 4) = o1;
        }

        const float av[8] = { a0.x, a0.y, a0.z, a0.w, a1.x, a1.y, a1.z, a1.w };
#pragma unroll
        for (int kk = 0; kk < 8; ++kk) {
            const float a = av[kk];
            const float* wr = wbase + (long long)(k0 + kk) * NDH;
#pragma unroll
            for (int j = 0; j < 32; ++j) acc[j] += a * wr[j];
        }
    }

    // write partial sums: part[kc][token][dhOff..dhOff+32)
    const long long o = ((long long)kc * (NB * NS) + token) * NDH + dhOff;
#pragma unroll
    for (int j = 0; j < 32; j += 4) {
        *reinterpret_cast<float4*>(part + o + j) =
            make_float4(acc[j], acc[j + 1], acc[j + 2], acc[j + 3]);
    }
}

// ---------------------------------------------------------------------------
// K1b: logits[T] = relu(sum_kc part + b1) . w2 + b2. One wave per token.
// ---------------------------------------------------------------------------
__global__ __launch_bounds__(256) void k_reduce(
    const float* __restrict__ part, const float* __restrict__ b1,
    const float* __restrict__ w2, const float* __restrict__ b2,
    float* __restrict__ logits)
{
    const int T = blockIdx.x * 4 + (threadIdx.x >> 6);
    const int lane = threadIdx.x & 63;
    float s = 0.0f;
#pragma unroll
    for (int kc = 0; kc < KS; ++kc)
        s += part[((long long)kc * (NB * NS) + T) * NDH + lane];
    const float h = fmaxf(s + b1[lane], 0.0f);
    float p = h * w2[lane];
#pragma unroll
    for (int m = 1; m < 64; m <<= 1) p += __shfl_xor(p, m, 64);
    if (lane == 0) logits[T] = p + b2[0];
}

// ---------------------------------------------------------------------------
// K2: per-batch gumbel top-k via exact 32-bit radix select + O(C^2) ranking
// (comparator: key desc, index asc — matches jax.lax.top_k), plus
// log_softmax gather mean. One block per batch, 256 threads, with
// wave0-shuffle suffix-scan/threshold-select and wave-shuffle reductions.
// ---------------------------------------------------------------------------
__global__ __launch_bounds__(256) void k_topk(
    const float* __restrict__ logits, const float* __restrict__ noise,
    float* __restrict__ outIdx, float* __restrict__ outType,
    float* __restrict__ outLP, int* __restrict__ wsIdx)
{
    __shared__ unsigned int ukey[NS];
    __shared__ float rawl[NS];
    __shared__ unsigned int hist[256];
    __shared__ unsigned int candU[512];
    __shared__ int candIdx[512];
    __shared__ int sel[NK];
    __shared__ float redw[4];
    __shared__ unsigned int misc[3];   // 0: prefix, 1: rem, 2: candCount

    const int b = blockIdx.x;
    const int tid = threadIdx.x;
    const int lane = tid & 63;
    const int wid = tid >> 6;

    for (int e = tid; e < NS; e += 256) {
        const float l = logits[b * NS + e];
        const float u = noise[b * NS + e];
        const float g = -logf(-logf(u));
        unsigned int x = __float_as_uint(l + g);
        x = (x & 0x80000000u) ? ~x : (x | 0x80000000u);   // monotonic uint map
        ukey[e] = x;
        rawl[e] = l;
    }
    if (tid == 0) { misc[0] = 0u; misc[1] = NK; misc[2] = 0u; }
    __syncthreads();

    // exact radix select: after 4 passes misc[0] = T (32-bit threshold key)
    for (int pass = 0; pass < 4; ++pass) {
        const int shift = 24 - pass * 8;
        hist[tid] = 0u;
        __syncthreads();
        const unsigned int pfx = misc[0];
        const unsigned int rem = misc[1];
        for (int e = tid; e < NS; e += 256) {
            const unsigned int x = ukey[e];
            if (pass == 0 || (x >> (shift + 8)) == pfx)
                atomicAdd(&hist[(x >> shift) & 255u], 1u);
        }
        __syncthreads();
        if (tid < 64) {
            // lane l owns bins 4l..4l+3; suffix-sum entirely in-wave
            const unsigned int h0 = hist[4 * tid];
            const unsigned int h1 = hist[4 * tid + 1];
            const unsigned int h2 = hist[4 * tid + 2];
            const unsigned int h3 = hist[4 * tid + 3];
            const unsigned int g = h0 + h1 + h2 + h3;
            unsigned int s = g;
#pragma unroll
            for (int m = 1; m < 64; m <<= 1) {
                const unsigned int v = __shfl_down(s, m, 64);
                if (tid + m < 64) s += v;
            }
            const unsigned int Snext = s - g;   // sum over lanes > l
            const unsigned int s3 = Snext + h3;
            const unsigned int s2 = s3 + h2;
            const unsigned int s1 = s2 + h1;
            const unsigned int s0 = s1 + h0;
            const unsigned int ge[4] = { s0, s1, s2, s3 };
            const unsigned int gt[4] = { s1, s2, s3, Snext };
#pragma unroll
            for (int i = 0; i < 4; ++i) {
                if (ge[i] >= rem && gt[i] < rem) {       // unique bin
                    misc[0] = (pfx << 8) | (unsigned int)(4 * tid + i);
                    misc[1] = rem - gt[i];
                }
            }
        }
        __syncthreads();
    }

    const unsigned int T = misc[0];
    for (int e = tid; e < NS; e += 256) {
        if (ukey[e] >= T) {
            const unsigned int slot = atomicAdd(&misc[2], 1u);
            if (slot < 512u) { candU[slot] = ukey[e]; candIdx[slot] = e; }
        }
    }
    __syncthreads();
    const int C = (int)min(misc[2], 512u);

    // exact rank per candidate (C ~ 256): rank < NK -> emit at slot rank
    for (int c = tid; c < C; c += 256) {
        const unsigned int xu = candU[c];
        const int xi = candIdx[c];
        int r = 0;
        for (int j = 0; j < C; ++j) {
            const unsigned int yu = candU[j];
            r += (int)((yu > xu) || (yu == xu && candIdx[j] < xi));
        }
        if (r < NK) {
            outIdx[b * NK + r] = (float)xi;
            outType[b * NK + r] = 1.0f;   // FIXED_TYPE
            wsIdx[b * NK + r] = xi;
            sel[r] = xi;
        }
    }

    // log-softmax denominator over raw logits (wave-shuffle reductions)
    float lm = -INFINITY;
    for (int e = tid; e < NS; e += 256) lm = fmaxf(lm, rawl[e]);
#pragma unroll
    for (int m = 32; m; m >>= 1) lm = fmaxf(lm, __shfl_xor(lm, m, 64));
    if (lane == 0) redw[wid] = lm;
    __syncthreads();                     // also makes sel[] visible
    const float maxv = fmaxf(fmaxf(redw[0], redw[1]), fmaxf(redw[2], redw[3]));
    __syncthreads();
    float ls = 0.0f;
    for (int e = tid; e < NS; e += 256) ls += expf(rawl[e] - maxv);
#pragma unroll
    for (int m = 32; m; m >>= 1) ls += __shfl_xor(ls, m, 64);
    if (lane == 0) redw[wid] = ls;
    __syncthreads();
    const float lse = logf(redw[0] + redw[1] + redw[2] + redw[3]);
    __syncthreads();
    float contrib = rawl[sel[tid]] - maxv - lse;   // tid < NK == 256 always
#pragma unroll
    for (int m = 32; m; m >>= 1) contrib += __shfl_xor(contrib, m, 64);
    if (lane == 0) redw[wid] = contrib;
    __syncthreads();
    if (tid == 0) outLP[b] = (redw[0] + redw[1] + redw[2] + redw[3]) / (float)NK;
}

// ---------------------------------------------------------------------------
// K3: zero the selected rows of out0 (perturb value = TYPE_VALUES[1]*SCALE = 0)
// ---------------------------------------------------------------------------
__global__ __launch_bounds__(256) void k_zero_rows(
    const int* __restrict__ wsIdx, float* __restrict__ out0)
{
    const int blk = blockIdx.x;        // 0 .. NB*NK-1
    const int b = blk >> 8;
    const int r = blk & 255;
    const int row = wsIdx[b * NK + r];
    const float4 z = make_float4(0.f, 0.f, 0.f, 0.f);
    float4* p = reinterpret_cast<float4*>(out0 + ((long long)(b * NS + row)) * NH);
    p[threadIdx.x]       = z;
    p[threadIdx.x + 256] = z;
}

extern "C" void kernel_launch(void* const* d_in, const int* in_sizes, int n_in,
                              void* d_out, int out_size, void* d_ws, size_t ws_size,
                              hipStream_t stream) {
    const float* hs    = (const float*)d_in[0];   // (B,S,H) fp32
    const float* noise = (const float*)d_in[1];   // (B,S)   fp32
    const float* w1    = (const float*)d_in[2];   // (H,DH)
    const float* b1    = (const float*)d_in[3];   // (DH,)
    const float* w2    = (const float*)d_in[4];   // (DH,1)
    const float* b2    = (const float*)d_in[5];   // (1,)

    float* out0    = (float*)d_out;                       // (B,S,H) perturbed
    float* outIdx  = out0 + (long long)NB * NS * NH;      // (B,K) indices as float
    float* outType = outIdx + NB * NK;                    // (B,K) types as float
    float* outLP   = outType + NB * NK;                   // (B,)  log_prob

    float* logits = (float*)d_ws;                         // B*S floats
    int*   wsIdx  = (int*)d_ws + NB * NS;                 // B*K ints
    float* part   = (float*)d_ws + NB * NS + NB * NK;     // KS*B*S*DH floats (~33.5 MB)

    k_sel_gemm<<<256 * KS, 256, 0, stream>>>(hs, w1, out0, part);
    k_reduce<<<NB * NS / 4, 256, 0, stream>>>(part, b1, w2, b2, logits);
    k_topk<<<NB, 256, 0, stream>>>(logits, noise, outIdx, outType, outLP, wsIdx);
    k_zero_rows<<<NB * NK, 256, 0, stream>>>(wsIdx, out0);
}